// Round 15
// baseline (691.222 us; speedup 1.0000x reference)
//
#include <hip/hip_runtime.h>

typedef unsigned short u16;
typedef unsigned int   u32;
typedef unsigned long long u64;
typedef __attribute__((ext_vector_type(8))) short short8;
typedef __attribute__((ext_vector_type(4))) float f32x4;

#define NN 2048

__device__ __forceinline__ float b2f(u16 u){ union { u32 i; float f; } x; x.i = ((u32)u)<<16; return x.f; }
__device__ __forceinline__ u16 f2b(float f){
  u32 u = __float_as_uint(f);
  u32 r = (u + 0x7fffu + ((u>>16)&1u)) >> 16;
  return (u16)r;
}
__device__ __forceinline__ float ldf(const void* p, size_t i, int bf){
  return bf ? b2f(((const u16*)p)[i]) : ((const float*)p)[i];
}
__device__ __forceinline__ void splitbf(float v, u16& h, u16& l){
  h = f2b(v);
  l = f2b(v - b2f(h));
}

// ---------------- diagnostic sentinel (f32 out) ------------------------------
__global__ __launch_bounds__(256) void sentinel_kernel(float* __restrict__ out, float val){
  int g = blockIdx.x*256 + threadIdx.x;
  if (g < NN*64) out[g] = val;
}

// ---------------- dtype probe (parallel): fp32 words are 0 / 0x3F800000 -----
__global__ __launch_bounds__(256) void probe_kernel(const u32* __restrict__ ap, int* __restrict__ flag){
  int i = blockIdx.x*256 + threadIdx.x;   // 65536 words
  u32 w = ap[i];
  if (w != 0u && w != 0x3F800000u) atomicOr(flag, 1);
}

// ---------------- fused input processing: csc | negbits | prep ---------------
struct InputArgs {
  const void *Ap, *An, *x;
  int *ap_cnt, *ap_idx;
  u64 *last, *uni;
  float* xf;
  const void *wl1,*bl1,*wl2,*bl2,*wl3,*bl3,*wg1,*bg1,*wg2,*bg2,*wg3,*bg3,*wg4,*bg4,*wg5,*bg5,*wg6,*bg6;
  float *tl1,*tg1,*tl2,*tg2,*tl3,*tg3,*tg4,*tg5,*tg6;
  float *obl1,*obg1,*obl2,*obg2,*obl3,*obg3,*obg4,*obg5,*obg6;
  const int* flag;
};

__global__ __launch_bounds__(256) void input_kernel(InputArgs a){
  int bf = *a.flag;
  int b = blockIdx.x;
  if (b < 16384){
    size_t e = (size_t)b*256 + threadIdx.x;   // e = k*2048 + j
    int k = (int)(e >> 11), j = (int)(e & 2047);
    if (ldf(a.Ap, e, bf) > 0.f){
      int p = atomicAdd(&a.ap_cnt[j], 1);
      if (p < 64) a.ap_idx[j*64 + p] = k;
    }
  } else if (b < 16640){
    int g = (b - 16384)*256 + threadIdx.x;    // 65536
    int j = g & 2047, w = g >> 11;
    u64 bits = 0;
    for (int bb = 0; bb < 64; ++bb){
      float v = ldf(a.An, (size_t)(w*64 + bb)*NN + j, bf);
      bits |= (u64)(v > 0.f) << bb;
    }
    a.last[(size_t)j*32 + w] = bits;
    a.uni [(size_t)j*32 + w] = bits;
  } else {
    int t = (b - 16640)*256 + threadIdx.x;    // 131072 threads
    for (size_t i = t; i < (size_t)NN*512; i += 131072) a.xf[i] = ldf(a.x, i, bf);
    if (t < 256*512){ int n = t>>9, k = t&511; a.tl1[t] = ldf(a.wl1, (size_t)k*256 + n, bf); }
    if (t < 256*256){ int n = t>>8, k = t&255; a.tg1[t] = ldf(a.wg1, (size_t)k*256 + n, bf); }
    if (t <  64*256){ int n = t>>8, k = t&255; a.tl2[t] = (n < 62) ? ldf(a.wl2, (size_t)k*62 + n, bf) : 0.f; }
    if (t <  64*64){
      int n = t>>6, k = t&63;
      a.tg2[t] = (n < 62 && k < 62) ? ldf(a.wg2, (size_t)k*62 + n, bf) : 0.f;
      a.tl3[t] = (k < 62) ? ldf(a.wl3, (size_t)k*64 + n, bf) : 0.f;
      a.tg3[t] = ldf(a.wg3, (size_t)k*64 + n, bf);
      a.tg4[t] = ldf(a.wg4, (size_t)k*64 + n, bf);
      a.tg5[t] = ldf(a.wg5, (size_t)k*64 + n, bf);
      a.tg6[t] = ldf(a.wg6, (size_t)k*64 + n, bf);
    }
    if (t < 256){ a.obl1[t] = ldf(a.bl1, t, bf); a.obg1[t] = ldf(a.bg1, t, bf); }
    if (t < 64){
      a.obl2[t] = (t < 62) ? ldf(a.bl2, t, bf) : 0.f;
      a.obg2[t] = (t < 62) ? ldf(a.bg2, t, bf) : 0.f;
      a.obl3[t] = ldf(a.bl3, t, bf);
      a.obg3[t] = ldf(a.bg3, t, bf);
      a.obg4[t] = ldf(a.bg4, t, bf);
      a.obg5[t] = ldf(a.bg5, t, bf);
      a.obg6[t] = ldf(a.bg6, t, bf);
    }
  }
}

// --------------- fused expand + 64x64 bit transpose + deg -------------------
__global__ __launch_bounds__(64) void bitstep_kernel(const u64* __restrict__ src, u64* __restrict__ dst,
                                                     u64* __restrict__ uni,
                                                     const int* __restrict__ cnt, const int* __restrict__ idx,
                                                     u64* __restrict__ rowb, int* __restrict__ deg,
                                                     int doExpand){
  __shared__ u64 lds[64];
  int wi = blockIdx.x, wj = blockIdx.y;
  int t = threadIdx.x;
  int j = wj*64 + t;
  u64 u;
  if (doExpand){
    int c = cnt[j]; c = (c > 64) ? 64 : c;
    const int* lst = idx + j*64;
    u64 acc = 0;
    for (int s = 0; s < c; ++s) acc |= src[(size_t)lst[s]*32 + wi];
    dst[(size_t)j*32 + wi] = acc;
    u = uni[(size_t)j*32 + wi] | acc;
    uni[(size_t)j*32 + wi] = u;
  } else {
    u = uni[(size_t)j*32 + wi];
  }
  lds[t] = u;
  __syncthreads();
  u64 out = 0;
#pragma unroll
  for (int tt = 0; tt < 64; ++tt) out |= ((lds[tt] >> t) & 1ULL) << tt;
  rowb[(size_t)(wi*64 + t)*32 + wj] = out;
  atomicAdd(&deg[wi*64 + t], (int)__popcll(out));
}

// --------------- split-bf16 MFMA GEMM: C[i][n] = sum_k A[i][k]*Bt[n][k] -----
// MODE 0: + bias[n] ; MODE 1: * 1/sqrt(deg[i]+1)
template<int MODE>
__global__ __launch_bounds__(256) void mgemm_kernel(const float* __restrict__ A, const float* __restrict__ Bt,
                                                    int N, int K,
                                                    const float* __restrict__ bias, const int* __restrict__ deg,
                                                    float* __restrict__ outF){
  constexpr int LDT = 72;
  __shared__ u16 Ah[64*LDT], Al[64*LDT], Bh[64*LDT], Bl[64*LDT];
  const int m0 = blockIdx.x*64, n0 = blockIdx.y*64;
  const int tid = threadIdx.x;
  const int wave = tid >> 6, lane = tid & 63;
  const int wm = (wave>>1)*32, wn = (wave&1)*32;
  const int q = lane >> 4, l16 = lane & 15;
  f32x4 acc00 = {}, acc01 = {}, acc10 = {}, acc11 = {};
  const int sr = tid >> 2, sc = (tid & 3)*16;
  for (int k0 = 0; k0 < K; k0 += 64){
    const float* Ag = A  + (size_t)(m0+sr)*K + k0 + sc;
    const float* Bg = Bt + (size_t)(n0+sr)*K + k0 + sc;
#pragma unroll
    for (int v4 = 0; v4 < 4; ++v4){
      float4 av = ((const float4*)Ag)[v4];
      float4 bv = ((const float4*)Bg)[v4];
      int o = sr*LDT + sc + v4*4;
      splitbf(av.x, Ah[o+0], Al[o+0]); splitbf(av.y, Ah[o+1], Al[o+1]);
      splitbf(av.z, Ah[o+2], Al[o+2]); splitbf(av.w, Ah[o+3], Al[o+3]);
      splitbf(bv.x, Bh[o+0], Bl[o+0]); splitbf(bv.y, Bh[o+1], Bl[o+1]);
      splitbf(bv.z, Bh[o+2], Bl[o+2]); splitbf(bv.w, Bh[o+3], Bl[o+3]);
    }
    __syncthreads();
#pragma unroll
    for (int ks = 0; ks < 2; ++ks){
      const int kb = ks*32 + q*8;
      short8 ah0 = *(const short8*)&Ah[(wm      + l16)*LDT + kb];
      short8 al0 = *(const short8*)&Al[(wm      + l16)*LDT + kb];
      short8 ah1 = *(const short8*)&Ah[(wm + 16 + l16)*LDT + kb];
      short8 al1 = *(const short8*)&Al[(wm + 16 + l16)*LDT + kb];
      short8 bh0 = *(const short8*)&Bh[(wn      + l16)*LDT + kb];
      short8 bl0 = *(const short8*)&Bl[(wn      + l16)*LDT + kb];
      short8 bh1 = *(const short8*)&Bh[(wn + 16 + l16)*LDT + kb];
      short8 bl1 = *(const short8*)&Bl[(wn + 16 + l16)*LDT + kb];
      acc00 = __builtin_amdgcn_mfma_f32_16x16x32_bf16(ah0, bh0, acc00, 0, 0, 0);
      acc00 = __builtin_amdgcn_mfma_f32_16x16x32_bf16(ah0, bl0, acc00, 0, 0, 0);
      acc00 = __builtin_amdgcn_mfma_f32_16x16x32_bf16(al0, bh0, acc00, 0, 0, 0);
      acc01 = __builtin_amdgcn_mfma_f32_16x16x32_bf16(ah0, bh1, acc01, 0, 0, 0);
      acc01 = __builtin_amdgcn_mfma_f32_16x16x32_bf16(ah0, bl1, acc01, 0, 0, 0);
      acc01 = __builtin_amdgcn_mfma_f32_16x16x32_bf16(al0, bh1, acc01, 0, 0, 0);
      acc10 = __builtin_amdgcn_mfma_f32_16x16x32_bf16(ah1, bh0, acc10, 0, 0, 0);
      acc10 = __builtin_amdgcn_mfma_f32_16x16x32_bf16(ah1, bl0, acc10, 0, 0, 0);
      acc10 = __builtin_amdgcn_mfma_f32_16x16x32_bf16(al1, bh0, acc10, 0, 0, 0);
      acc11 = __builtin_amdgcn_mfma_f32_16x16x32_bf16(ah1, bh1, acc11, 0, 0, 0);
      acc11 = __builtin_amdgcn_mfma_f32_16x16x32_bf16(ah1, bl1, acc11, 0, 0, 0);
      acc11 = __builtin_amdgcn_mfma_f32_16x16x32_bf16(al1, bh1, acc11, 0, 0, 0);
    }
    __syncthreads();
  }
#pragma unroll
  for (int mi = 0; mi < 2; ++mi)
#pragma unroll
  for (int ni = 0; ni < 2; ++ni){
    f32x4 a = (mi == 0) ? ((ni == 0) ? acc00 : acc01) : ((ni == 0) ? acc10 : acc11);
#pragma unroll
    for (int r = 0; r < 4; ++r){
      int i = m0 + wm + mi*16 + q*4 + r;
      int n = n0 + wn + ni*16 + l16;
      float v = a[r];
      if constexpr (MODE == 0) v += bias[n];
      else                     v *= 1.0f / sqrtf((float)(deg[i] + 1));
      outF[(size_t)i*N + n] = v;
    }
  }
}

// --------------- fused dual GEMM for N=64 stages ----------------------------
// Phase 1: h = A@Bt1^T + bias1 (rows m0..m0+63, all 64 cols) -> hOut + LDS.
// Phase 2: zs = (h@Bt2^T) * 1/sqrt(deg+1) -> zsOut. Numerics == two mgemms.
__global__ __launch_bounds__(256) void mgemm2_kernel(const float* __restrict__ A, const float* __restrict__ Bt1,
                                                     int K1, const float* __restrict__ bias1,
                                                     const float* __restrict__ Bt2, const int* __restrict__ deg,
                                                     float* __restrict__ hOut, float* __restrict__ zsOut){
  constexpr int LDT = 72;
  __shared__ u16 Ah[64*LDT], Al[64*LDT], Bh[64*LDT], Bl[64*LDT];
  const int m0 = blockIdx.x*64;
  const int tid = threadIdx.x;
  const int wave = tid >> 6, lane = tid & 63;
  const int wm = (wave>>1)*32, wn = (wave&1)*32;
  const int q = lane >> 4, l16 = lane & 15;
  const int sr = tid >> 2, sc = (tid & 3)*16;
  f32x4 acc00 = {}, acc01 = {}, acc10 = {}, acc11 = {};
  // ---- phase 1: h = A@Bt1 + bias1 ----
  for (int k0 = 0; k0 < K1; k0 += 64){
    const float* Ag = A   + (size_t)(m0+sr)*K1 + k0 + sc;
    const float* Bg = Bt1 + (size_t)sr*K1 + k0 + sc;
#pragma unroll
    for (int v4 = 0; v4 < 4; ++v4){
      float4 av = ((const float4*)Ag)[v4];
      float4 bv = ((const float4*)Bg)[v4];
      int o = sr*LDT + sc + v4*4;
      splitbf(av.x, Ah[o+0], Al[o+0]); splitbf(av.y, Ah[o+1], Al[o+1]);
      splitbf(av.z, Ah[o+2], Al[o+2]); splitbf(av.w, Ah[o+3], Al[o+3]);
      splitbf(bv.x, Bh[o+0], Bl[o+0]); splitbf(bv.y, Bh[o+1], Bl[o+1]);
      splitbf(bv.z, Bh[o+2], Bl[o+2]); splitbf(bv.w, Bh[o+3], Bl[o+3]);
    }
    __syncthreads();
#pragma unroll
    for (int ks = 0; ks < 2; ++ks){
      const int kb = ks*32 + q*8;
      short8 ah0 = *(const short8*)&Ah[(wm      + l16)*LDT + kb];
      short8 al0 = *(const short8*)&Al[(wm      + l16)*LDT + kb];
      short8 ah1 = *(const short8*)&Ah[(wm + 16 + l16)*LDT + kb];
      short8 al1 = *(const short8*)&Al[(wm + 16 + l16)*LDT + kb];
      short8 bh0 = *(const short8*)&Bh[(wn      + l16)*LDT + kb];
      short8 bl0 = *(const short8*)&Bl[(wn      + l16)*LDT + kb];
      short8 bh1 = *(const short8*)&Bh[(wn + 16 + l16)*LDT + kb];
      short8 bl1 = *(const short8*)&Bl[(wn + 16 + l16)*LDT + kb];
      acc00 = __builtin_amdgcn_mfma_f32_16x16x32_bf16(ah0, bh0, acc00, 0, 0, 0);
      acc00 = __builtin_amdgcn_mfma_f32_16x16x32_bf16(ah0, bl0, acc00, 0, 0, 0);
      acc00 = __builtin_amdgcn_mfma_f32_16x16x32_bf16(al0, bh0, acc00, 0, 0, 0);
      acc01 = __builtin_amdgcn_mfma_f32_16x16x32_bf16(ah0, bh1, acc01, 0, 0, 0);
      acc01 = __builtin_amdgcn_mfma_f32_16x16x32_bf16(ah0, bl1, acc01, 0, 0, 0);
      acc01 = __builtin_amdgcn_mfma_f32_16x16x32_bf16(al0, bh1, acc01, 0, 0, 0);
      acc10 = __builtin_amdgcn_mfma_f32_16x16x32_bf16(ah1, bh0, acc10, 0, 0, 0);
      acc10 = __builtin_amdgcn_mfma_f32_16x16x32_bf16(ah1, bl0, acc10, 0, 0, 0);
      acc10 = __builtin_amdgcn_mfma_f32_16x16x32_bf16(al1, bh0, acc10, 0, 0, 0);
      acc11 = __builtin_amdgcn_mfma_f32_16x16x32_bf16(ah1, bh1, acc11, 0, 0, 0);
      acc11 = __builtin_amdgcn_mfma_f32_16x16x32_bf16(ah1, bl1, acc11, 0, 0, 0);
      acc11 = __builtin_amdgcn_mfma_f32_16x16x32_bf16(al1, bh1, acc11, 0, 0, 0);
    }
    __syncthreads();
  }
  // ---- epilogue 1: h -> global + LDS (A-operand layout for phase 2) ----
#pragma unroll
  for (int mi = 0; mi < 2; ++mi)
#pragma unroll
  for (int ni = 0; ni < 2; ++ni){
    f32x4 a = (mi == 0) ? ((ni == 0) ? acc00 : acc01) : ((ni == 0) ? acc10 : acc11);
#pragma unroll
    for (int r = 0; r < 4; ++r){
      int il = wm + mi*16 + q*4 + r;
      int n  = wn + ni*16 + l16;
      float v = a[r] + bias1[n];
      hOut[(size_t)(m0 + il)*64 + n] = v;
      u16 hh, ll;
      splitbf(v, hh, ll);
      Ah[il*LDT + n] = hh;
      Al[il*LDT + n] = ll;
    }
  }
  __syncthreads();
  // ---- phase 2 staging: Bt2 (64x64) -> Bh/Bl ----
  {
    const float* Bg = Bt2 + (size_t)sr*64 + sc;
#pragma unroll
    for (int v4 = 0; v4 < 4; ++v4){
      float4 bv = ((const float4*)Bg)[v4];
      int o = sr*LDT + sc + v4*4;
      splitbf(bv.x, Bh[o+0], Bl[o+0]); splitbf(bv.y, Bh[o+1], Bl[o+1]);
      splitbf(bv.z, Bh[o+2], Bl[o+2]); splitbf(bv.w, Bh[o+3], Bl[o+3]);
    }
  }
  __syncthreads();
  f32x4 z00 = {}, z01 = {}, z10 = {}, z11 = {};
#pragma unroll
  for (int ks = 0; ks < 2; ++ks){
    const int kb = ks*32 + q*8;
    short8 ah0 = *(const short8*)&Ah[(wm      + l16)*LDT + kb];
    short8 al0 = *(const short8*)&Al[(wm      + l16)*LDT + kb];
    short8 ah1 = *(const short8*)&Ah[(wm + 16 + l16)*LDT + kb];
    short8 al1 = *(const short8*)&Al[(wm + 16 + l16)*LDT + kb];
    short8 bh0 = *(const short8*)&Bh[(wn      + l16)*LDT + kb];
    short8 bl0 = *(const short8*)&Bl[(wn      + l16)*LDT + kb];
    short8 bh1 = *(const short8*)&Bh[(wn + 16 + l16)*LDT + kb];
    short8 bl1 = *(const short8*)&Bl[(wn + 16 + l16)*LDT + kb];
    z00 = __builtin_amdgcn_mfma_f32_16x16x32_bf16(ah0, bh0, z00, 0, 0, 0);
    z00 = __builtin_amdgcn_mfma_f32_16x16x32_bf16(ah0, bl0, z00, 0, 0, 0);
    z00 = __builtin_amdgcn_mfma_f32_16x16x32_bf16(al0, bh0, z00, 0, 0, 0);
    z01 = __builtin_amdgcn_mfma_f32_16x16x32_bf16(ah0, bh1, z01, 0, 0, 0);
    z01 = __builtin_amdgcn_mfma_f32_16x16x32_bf16(ah0, bl1, z01, 0, 0, 0);
    z01 = __builtin_amdgcn_mfma_f32_16x16x32_bf16(al0, bh1, z01, 0, 0, 0);
    z10 = __builtin_amdgcn_mfma_f32_16x16x32_bf16(ah1, bh0, z10, 0, 0, 0);
    z10 = __builtin_amdgcn_mfma_f32_16x16x32_bf16(ah1, bl0, z10, 0, 0, 0);
    z10 = __builtin_amdgcn_mfma_f32_16x16x32_bf16(al1, bh0, z10, 0, 0, 0);
    z11 = __builtin_amdgcn_mfma_f32_16x16x32_bf16(ah1, bh1, z11, 0, 0, 0);
    z11 = __builtin_amdgcn_mfma_f32_16x16x32_bf16(ah1, bl1, z11, 0, 0, 0);
    z11 = __builtin_amdgcn_mfma_f32_16x16x32_bf16(al1, bh1, z11, 0, 0, 0);
  }
#pragma unroll
  for (int mi = 0; mi < 2; ++mi)
#pragma unroll
  for (int ni = 0; ni < 2; ++ni){
    f32x4 a = (mi == 0) ? ((ni == 0) ? z00 : z01) : ((ni == 0) ? z10 : z11);
#pragma unroll
    for (int r = 0; r < 4; ++r){
      int i = m0 + wm + mi*16 + q*4 + r;
      int n = wn + ni*16 + l16;
      zsOut[(size_t)i*64 + n] = a[r] * (1.0f / sqrtf((float)(deg[i] + 1)));
    }
  }
}

// --------------- fused split-K agg + last-block GCN epilogue ----------------
template<int F>
__global__ __launch_bounds__(256) void magf_kernel(const float* __restrict__ zs,
                                                   const u64* __restrict__ rowb,
                                                   float* __restrict__ part, int KCH, int KS,
                                                   int* __restrict__ cnt,
                                                   const float* __restrict__ h,
                                                   const float* __restrict__ bias,
                                                   const int* __restrict__ deg,
                                                   float wgt, int doRelu,
                                                   float* __restrict__ outF, float* __restrict__ outD){
  const int m0 = blockIdx.x*64, n0 = blockIdx.y*64, kc0 = blockIdx.z*KCH;
  const int tid = threadIdx.x;
  const int wave = tid >> 6, lane = tid & 63;
  const int wm = (wave>>1)*32, wn = (wave&1)*32;
  const int q = lane >> 4, l16 = lane & 15;
  f32x4 acc00 = {}, acc01 = {}, acc10 = {}, acc11 = {};
  for (int k0 = kc0; k0 < kc0 + KCH; k0 += 64){
    const int wd = k0 >> 6;
    u64 w0 = rowb[(size_t)(m0 + wm      + l16)*32 + wd];
    u64 w1 = rowb[(size_t)(m0 + wm + 16 + l16)*32 + wd];
#pragma unroll
    for (int ks = 0; ks < 2; ++ks){
      const int kk = ks*32 + q*8;
      u32 by0 = (u32)(w0 >> kk) & 0xFFu;
      u32 by1 = (u32)(w1 >> kk) & 0xFFu;
      short8 a0, a1;
#pragma unroll
      for (int j = 0; j < 8; ++j){
        a0[j] = (short)(((by0 >> j) & 1u) ? 0x3F80 : 0);
        a1[j] = (short)(((by1 >> j) & 1u) ? 0x3F80 : 0);
      }
      const float* B0 = zs + (size_t)(k0 + kk)*F + n0;
      short8 bh0, bl0, bh1, bl1;
#pragma unroll
      for (int j = 0; j < 8; ++j){
        u16 hh, ll;
        splitbf(B0[(size_t)j*F + wn      + l16], hh, ll); bh0[j] = (short)hh; bl0[j] = (short)ll;
        splitbf(B0[(size_t)j*F + wn + 16 + l16], hh, ll); bh1[j] = (short)hh; bl1[j] = (short)ll;
      }
      acc00 = __builtin_amdgcn_mfma_f32_16x16x32_bf16(a0, bh0, acc00, 0, 0, 0);
      acc00 = __builtin_amdgcn_mfma_f32_16x16x32_bf16(a0, bl0, acc00, 0, 0, 0);
      acc01 = __builtin_amdgcn_mfma_f32_16x16x32_bf16(a0, bh1, acc01, 0, 0, 0);
      acc01 = __builtin_amdgcn_mfma_f32_16x16x32_bf16(a0, bl1, acc01, 0, 0, 0);
      acc10 = __builtin_amdgcn_mfma_f32_16x16x32_bf16(a1, bh0, acc10, 0, 0, 0);
      acc10 = __builtin_amdgcn_mfma_f32_16x16x32_bf16(a1, bl0, acc10, 0, 0, 0);
      acc11 = __builtin_amdgcn_mfma_f32_16x16x32_bf16(a1, bh1, acc11, 0, 0, 0);
      acc11 = __builtin_amdgcn_mfma_f32_16x16x32_bf16(a1, bl1, acc11, 0, 0, 0);
    }
  }
  float* p = part + (size_t)blockIdx.z*NN*F;
#pragma unroll
  for (int mi = 0; mi < 2; ++mi)
#pragma unroll
  for (int ni = 0; ni < 2; ++ni){
    f32x4 a = (mi == 0) ? ((ni == 0) ? acc00 : acc01) : ((ni == 0) ? acc10 : acc11);
#pragma unroll
    for (int r = 0; r < 4; ++r){
      int i = m0 + wm + mi*16 + q*4 + r;
      int n = n0 + wn + ni*16 + l16;
      p[(size_t)i*F + n] = a[r];
    }
  }
  // ---- last z-block for this (m,n) tile does the epilogue ----
  __threadfence();
  __shared__ int isLast;
  if (tid == 0)
    isLast = (atomicAdd(&cnt[blockIdx.y*32 + blockIdx.x], 1) == KS - 1);
  __syncthreads();
  if (!isLast) return;
  __threadfence();
  for (int e = tid; e < 64*64; e += 256){
    int il = e >> 6, nl = e & 63;
    int i = m0 + il, n = n0 + nl;
    size_t g = (size_t)i*F + n;
    float y = 0.f;
    for (int s = 0; s < KS; ++s) y += part[(size_t)s*NN*F + g];
    float di = 1.0f / sqrtf((float)(deg[i] + 1));
    float o = di*(y + zs[g]) + bias[n];
    if (doRelu) o = fmaxf(o, 0.f);
    float xn = h[g] + wgt*o;
    outF[g] = xn;
    if (outD) outD[g] = xn;
  }
}

static inline char* wso(void* ws, size_t& off, size_t bytes){
  char* p = (char*)ws + off;
  off += (bytes + 255) & ~(size_t)255;
  return p;
}

extern "C" void kernel_launch(void* const* d_in, const int* in_sizes, int n_in,
                              void* d_out, int out_size, void* d_ws, size_t ws_size,
                              hipStream_t stream){
  // ---- regression guards ----
  static const int EXP_SIZES[21] = {
    2048*512, 2048*2048, 2048*2048,
    512*256, 256, 256*62, 62, 62*64, 64,
    256*256, 256, 62*62, 62, 64*64, 64,
    64*64, 64, 64*64, 64, 64*64, 64
  };
  float sentinel = 0.f;
  if (n_in != 21) sentinel = 8800000.f;
  if (sentinel == 0.f){
    for (int i = 0; i < 21; ++i)
      if (in_sizes[i] != EXP_SIZES[i]){ sentinel = 100000.f*(float)(i+1); break; }
  }
  if (sentinel == 0.f && out_size != 2048*64) sentinel = 6600000.f;

  // ---- workspace layout (zeroed prefix: dflag|ap_cnt|deg6|cnt6) ----
  size_t off = 0;
  int*   dflag  = (int*)  wso(d_ws, off, 256);
  int*   ap_cnt = (int*)  wso(d_ws, off, NN*4);
  int*   deg6   = (int*)  wso(d_ws, off, (size_t)6*NN*4);
  int*   cnt6   = (int*)  wso(d_ws, off, (size_t)6*128*4);
  size_t zero_bytes = off;
  int*   ap_idx = (int*)  wso(d_ws, off, NN*64*4);
  u64*   colA   = (u64*)  wso(d_ws, off, (size_t)NN*32*8);
  u64*   colB   = (u64*)  wso(d_ws, off, (size_t)NN*32*8);
  u64*   colU   = (u64*)  wso(d_ws, off, (size_t)NN*32*8);
  u64*   rowb6  = (u64*)  wso(d_ws, off, (size_t)6*NN*32*8);
  float* xf     = (float*)wso(d_ws, off, (size_t)NN*512*4);
  float* part   = (float*)wso(d_ws, off, (size_t)16*NN*64*4);   // 8 MB split-K partials
  float *tl1 = (float*)wso(d_ws, off, 256*512*4), *tg1 = (float*)wso(d_ws, off, 256*256*4);
  float *tl2 = (float*)wso(d_ws, off,  64*256*4), *tg2 = (float*)wso(d_ws, off,  64*64*4);
  float *tl3 = (float*)wso(d_ws, off,   64*64*4), *tg3 = (float*)wso(d_ws, off,  64*64*4);
  float *tg4 = (float*)wso(d_ws, off,   64*64*4), *tg5 = (float*)wso(d_ws, off,  64*64*4);
  float *tg6 = (float*)wso(d_ws, off,   64*64*4);
  float *obl1 = (float*)wso(d_ws, off, 256*4), *obg1 = (float*)wso(d_ws, off, 256*4);
  float *obl2 = (float*)wso(d_ws, off, 64*4),  *obg2 = (float*)wso(d_ws, off, 64*4);
  float *obl3 = (float*)wso(d_ws, off, 64*4),  *obg3 = (float*)wso(d_ws, off, 64*4);
  float *obg4 = (float*)wso(d_ws, off, 64*4),  *obg5 = (float*)wso(d_ws, off, 64*4);
  float *obg6 = (float*)wso(d_ws, off, 64*4);
  float* hF   = (float*)wso(d_ws, off, (size_t)NN*256*4);
  float* zs   = (float*)wso(d_ws, off, (size_t)NN*256*4);
  float* xF   = (float*)wso(d_ws, off, (size_t)NN*256*4);

  if (sentinel == 0.f && off > ws_size) sentinel = 7700000.f;

  if (sentinel != 0.f){
    sentinel_kernel<<<(NN*64 + 255)/256, 256, 0, stream>>>((float*)d_out, sentinel);
    return;
  }

  const void* x_in = d_in[0];
  const void* An   = d_in[1];
  const void* Ap   = d_in[2];

  hipMemsetAsync(d_ws, 0, zero_bytes, stream);   // dflag + ap_cnt + deg6 + cnt6
  probe_kernel<<<256, 256, 0, stream>>>((const u32*)Ap, dflag);

  InputArgs ia;
  ia.Ap = Ap; ia.An = An; ia.x = x_in;
  ia.ap_cnt = ap_cnt; ia.ap_idx = ap_idx;
  ia.last = colA; ia.uni = colU; ia.xf = xf;
  ia.wl1=d_in[3];  ia.bl1=d_in[4];
  ia.wl2=d_in[5];  ia.bl2=d_in[6];
  ia.wl3=d_in[7];  ia.bl3=d_in[8];
  ia.wg1=d_in[9];  ia.bg1=d_in[10];
  ia.wg2=d_in[11]; ia.bg2=d_in[12];
  ia.wg3=d_in[13]; ia.bg3=d_in[14];
  ia.wg4=d_in[15]; ia.bg4=d_in[16];
  ia.wg5=d_in[17]; ia.bg5=d_in[18];
  ia.wg6=d_in[19]; ia.bg6=d_in[20];
  ia.tl1=tl1; ia.tg1=tg1; ia.tl2=tl2; ia.tg2=tg2; ia.tl3=tl3;
  ia.tg3=tg3; ia.tg4=tg4; ia.tg5=tg5; ia.tg6=tg6;
  ia.obl1=obl1; ia.obg1=obg1; ia.obl2=obl2; ia.obg2=obg2; ia.obl3=obl3;
  ia.obg3=obg3; ia.obg4=obg4; ia.obg5=obg5; ia.obg6=obg6;
  ia.flag = dflag;
  input_kernel<<<17152, 256, 0, stream>>>(ia);

  // ---- bit pipeline: 6 fused expand+transpose+deg steps ----
  {
    u64 *src = colA, *dst = colB;
    for (int s = 0; s < 6; ++s){
      bitstep_kernel<<<dim3(32,32), 64, 0, stream>>>(src, dst, colU, ap_cnt, ap_idx,
                                                     rowb6 + (size_t)s*NN*32, deg6 + s*NN,
                                                     s > 0 ? 1 : 0);
      if (s > 0){ u64* t = src; src = dst; dst = t; }
    }
  }

  const u64* rb[6]; const int* dg[6];
  for (int s = 0; s < 6; ++s){ rb[s] = rowb6 + (size_t)s*NN*32; dg[s] = deg6 + s*NN; }

  // ---- stage 0 (F=256) ----
  mgemm_kernel<0><<<dim3(32,4), 256, 0, stream>>>(xf, tl1, 256, 512, obl1, nullptr, hF);
  mgemm_kernel<1><<<dim3(32,4), 256, 0, stream>>>(hF, tg1, 256, 256, nullptr, dg[0], zs);
  magf_kernel<256><<<dim3(32,4,4), 256, 0, stream>>>(zs, rb[0], part, 512, 4, cnt6 + 0*128,
                                                     hF, obg1, dg[0], 1.0f, 1, xF, nullptr);
  // ---- stage 1 ----
  mgemm2_kernel<<<dim3(32,1), 256, 0, stream>>>(xF, tl2, 256, obl2, tg2, dg[1], hF, zs);
  magf_kernel<64><<<dim3(32,1,8), 256, 0, stream>>>(zs, rb[1], part, 256, 8, cnt6 + 1*128,
                                                    hF, obg2, dg[1], 1.0f, 1, xF, nullptr);
  // ---- stage 2 ----
  mgemm2_kernel<<<dim3(32,1), 256, 0, stream>>>(xF, tl3, 64, obl3, tg3, dg[2], hF, zs);
  magf_kernel<64><<<dim3(32,1,8), 256, 0, stream>>>(zs, rb[2], part, 256, 8, cnt6 + 2*128,
                                                    hF, obg3, dg[2], 0.5f, 1, xF, nullptr);
  // ---- stages 3-5 ----
  const float* tgs[3]  = {tg4, tg5, tg6};
  const float* obs[3]  = {obg4, obg5, obg6};
  const float  wg3_[3] = {0.5f, 0.25f, 0.25f};
  const int    rl3_[3] = {1, 1, 0};
  for (int s = 3; s < 6; ++s){
    mgemm_kernel<1><<<dim3(32,1), 256, 0, stream>>>(xF, tgs[s-3], 64, 64, nullptr, dg[s], zs);
    float* outD = (s == 5) ? (float*)d_out : nullptr;
    magf_kernel<64><<<dim3(32,1,8), 256, 0, stream>>>(zs, rb[s], part, 256, 8, cnt6 + s*128,
                                                      xF, obs[s-3], dg[s], wg3_[s-3], rl3_[s-3],
                                                      xF, outD);
  }
}

// Round 16
// 358.747 us; speedup vs baseline: 1.9268x; 1.9268x over previous
//
#include <hip/hip_runtime.h>

typedef unsigned short u16;
typedef unsigned int   u32;
typedef unsigned long long u64;
typedef __attribute__((ext_vector_type(8))) short short8;
typedef __attribute__((ext_vector_type(4))) float f32x4;

#define NN 2048

__device__ __forceinline__ float b2f(u16 u){ union { u32 i; float f; } x; x.i = ((u32)u)<<16; return x.f; }
__device__ __forceinline__ u16 f2b(float f){
  u32 u = __float_as_uint(f);
  u32 r = (u + 0x7fffu + ((u>>16)&1u)) >> 16;
  return (u16)r;
}
__device__ __forceinline__ float ldf(const void* p, size_t i, int bf){
  return bf ? b2f(((const u16*)p)[i]) : ((const float*)p)[i];
}
__device__ __forceinline__ void splitbf(float v, u16& h, u16& l){
  h = f2b(v);
  l = f2b(v - b2f(h));
}

// ---------------- diagnostic sentinel (f32 out) ------------------------------
__global__ __launch_bounds__(256) void sentinel_kernel(float* __restrict__ out, float val){
  int g = blockIdx.x*256 + threadIdx.x;
  if (g < NN*64) out[g] = val;
}

// ---------------- dtype probe (parallel): fp32 words are 0 / 0x3F800000 -----
__global__ __launch_bounds__(256) void probe_kernel(const u32* __restrict__ ap, int* __restrict__ flag){
  int i = blockIdx.x*256 + threadIdx.x;   // 65536 words
  u32 w = ap[i];
  if (w != 0u && w != 0x3F800000u) atomicOr(flag, 1);
}

// ---------------- fused input processing: csc | negbits | prep ---------------
struct InputArgs {
  const void *Ap, *An, *x;
  int *ap_cnt, *ap_idx;
  u64 *last, *uni;
  float* xf;
  const void *wl1,*bl1,*wl2,*bl2,*wl3,*bl3,*wg1,*bg1,*wg2,*bg2,*wg3,*bg3,*wg4,*bg4,*wg5,*bg5,*wg6,*bg6;
  float *tl1,*tg1,*tl2,*tg2,*tl3,*tg3,*tg4,*tg5,*tg6;
  float *obl1,*obg1,*obl2,*obg2,*obl3,*obg3,*obg4,*obg5,*obg6;
  const int* flag;
};

__global__ __launch_bounds__(256) void input_kernel(InputArgs a){
  int bf = *a.flag;
  int b = blockIdx.x;
  if (b < 16384){
    size_t e = (size_t)b*256 + threadIdx.x;   // e = k*2048 + j
    int k = (int)(e >> 11), j = (int)(e & 2047);
    if (ldf(a.Ap, e, bf) > 0.f){
      int p = atomicAdd(&a.ap_cnt[j], 1);
      if (p < 64) a.ap_idx[j*64 + p] = k;
    }
  } else if (b < 16640){
    int g = (b - 16384)*256 + threadIdx.x;    // 65536
    int j = g & 2047, w = g >> 11;
    u64 bits = 0;
    for (int bb = 0; bb < 64; ++bb){
      float v = ldf(a.An, (size_t)(w*64 + bb)*NN + j, bf);
      bits |= (u64)(v > 0.f) << bb;
    }
    a.last[(size_t)j*32 + w] = bits;
    a.uni [(size_t)j*32 + w] = bits;
  } else {
    int t = (b - 16640)*256 + threadIdx.x;    // 131072 threads
    for (size_t i = t; i < (size_t)NN*512; i += 131072) a.xf[i] = ldf(a.x, i, bf);
    if (t < 256*512){ int n = t>>9, k = t&511; a.tl1[t] = ldf(a.wl1, (size_t)k*256 + n, bf); }
    if (t < 256*256){ int n = t>>8, k = t&255; a.tg1[t] = ldf(a.wg1, (size_t)k*256 + n, bf); }
    if (t <  64*256){ int n = t>>8, k = t&255; a.tl2[t] = (n < 62) ? ldf(a.wl2, (size_t)k*62 + n, bf) : 0.f; }
    if (t <  64*64){
      int n = t>>6, k = t&63;
      a.tg2[t] = (n < 62 && k < 62) ? ldf(a.wg2, (size_t)k*62 + n, bf) : 0.f;
      a.tl3[t] = (k < 62) ? ldf(a.wl3, (size_t)k*64 + n, bf) : 0.f;
      a.tg3[t] = ldf(a.wg3, (size_t)k*64 + n, bf);
      a.tg4[t] = ldf(a.wg4, (size_t)k*64 + n, bf);
      a.tg5[t] = ldf(a.wg5, (size_t)k*64 + n, bf);
      a.tg6[t] = ldf(a.wg6, (size_t)k*64 + n, bf);
    }
    if (t < 256){ a.obl1[t] = ldf(a.bl1, t, bf); a.obg1[t] = ldf(a.bg1, t, bf); }
    if (t < 64){
      a.obl2[t] = (t < 62) ? ldf(a.bl2, t, bf) : 0.f;
      a.obg2[t] = (t < 62) ? ldf(a.bg2, t, bf) : 0.f;
      a.obl3[t] = ldf(a.bl3, t, bf);
      a.obg3[t] = ldf(a.bg3, t, bf);
      a.obg4[t] = ldf(a.bg4, t, bf);
      a.obg5[t] = ldf(a.bg5, t, bf);
      a.obg6[t] = ldf(a.bg6, t, bf);
    }
  }
}

// --------------- fused expand + 64x64 bit transpose + deg -------------------
__global__ __launch_bounds__(64) void bitstep_kernel(const u64* __restrict__ src, u64* __restrict__ dst,
                                                     u64* __restrict__ uni,
                                                     const int* __restrict__ cnt, const int* __restrict__ idx,
                                                     u64* __restrict__ rowb, int* __restrict__ deg,
                                                     int doExpand){
  __shared__ u64 lds[64];
  int wi = blockIdx.x, wj = blockIdx.y;
  int t = threadIdx.x;
  int j = wj*64 + t;
  u64 u;
  if (doExpand){
    int c = cnt[j]; c = (c > 64) ? 64 : c;
    const int* lst = idx + j*64;
    u64 acc = 0;
    for (int s = 0; s < c; ++s) acc |= src[(size_t)lst[s]*32 + wi];
    dst[(size_t)j*32 + wi] = acc;
    u = uni[(size_t)j*32 + wi] | acc;
    uni[(size_t)j*32 + wi] = u;
  } else {
    u = uni[(size_t)j*32 + wi];
  }
  lds[t] = u;
  __syncthreads();
  u64 out = 0;
#pragma unroll
  for (int tt = 0; tt < 64; ++tt) out |= ((lds[tt] >> t) & 1ULL) << tt;
  rowb[(size_t)(wi*64 + t)*32 + wj] = out;
  atomicAdd(&deg[wi*64 + t], (int)__popcll(out));
}

// --------------- split-bf16 MFMA GEMM: C[i][n] = sum_k A[i][k]*Bt[n][k] -----
// MODE 0: + bias[n] ; MODE 1: * 1/sqrt(deg[i]+1)
template<int MODE>
__global__ __launch_bounds__(256) void mgemm_kernel(const float* __restrict__ A, const float* __restrict__ Bt,
                                                    int N, int K,
                                                    const float* __restrict__ bias, const int* __restrict__ deg,
                                                    float* __restrict__ outF){
  constexpr int LDT = 72;
  __shared__ u16 Ah[64*LDT], Al[64*LDT], Bh[64*LDT], Bl[64*LDT];
  const int m0 = blockIdx.x*64, n0 = blockIdx.y*64;
  const int tid = threadIdx.x;
  const int wave = tid >> 6, lane = tid & 63;
  const int wm = (wave>>1)*32, wn = (wave&1)*32;
  const int q = lane >> 4, l16 = lane & 15;
  f32x4 acc00 = {}, acc01 = {}, acc10 = {}, acc11 = {};
  const int sr = tid >> 2, sc = (tid & 3)*16;
  for (int k0 = 0; k0 < K; k0 += 64){
    const float* Ag = A  + (size_t)(m0+sr)*K + k0 + sc;
    const float* Bg = Bt + (size_t)(n0+sr)*K + k0 + sc;
#pragma unroll
    for (int v4 = 0; v4 < 4; ++v4){
      float4 av = ((const float4*)Ag)[v4];
      float4 bv = ((const float4*)Bg)[v4];
      int o = sr*LDT + sc + v4*4;
      splitbf(av.x, Ah[o+0], Al[o+0]); splitbf(av.y, Ah[o+1], Al[o+1]);
      splitbf(av.z, Ah[o+2], Al[o+2]); splitbf(av.w, Ah[o+3], Al[o+3]);
      splitbf(bv.x, Bh[o+0], Bl[o+0]); splitbf(bv.y, Bh[o+1], Bl[o+1]);
      splitbf(bv.z, Bh[o+2], Bl[o+2]); splitbf(bv.w, Bh[o+3], Bl[o+3]);
    }
    __syncthreads();
#pragma unroll
    for (int ks = 0; ks < 2; ++ks){
      const int kb = ks*32 + q*8;
      short8 ah0 = *(const short8*)&Ah[(wm      + l16)*LDT + kb];
      short8 al0 = *(const short8*)&Al[(wm      + l16)*LDT + kb];
      short8 ah1 = *(const short8*)&Ah[(wm + 16 + l16)*LDT + kb];
      short8 al1 = *(const short8*)&Al[(wm + 16 + l16)*LDT + kb];
      short8 bh0 = *(const short8*)&Bh[(wn      + l16)*LDT + kb];
      short8 bl0 = *(const short8*)&Bl[(wn      + l16)*LDT + kb];
      short8 bh1 = *(const short8*)&Bh[(wn + 16 + l16)*LDT + kb];
      short8 bl1 = *(const short8*)&Bl[(wn + 16 + l16)*LDT + kb];
      acc00 = __builtin_amdgcn_mfma_f32_16x16x32_bf16(ah0, bh0, acc00, 0, 0, 0);
      acc00 = __builtin_amdgcn_mfma_f32_16x16x32_bf16(ah0, bl0, acc00, 0, 0, 0);
      acc00 = __builtin_amdgcn_mfma_f32_16x16x32_bf16(al0, bh0, acc00, 0, 0, 0);
      acc01 = __builtin_amdgcn_mfma_f32_16x16x32_bf16(ah0, bh1, acc01, 0, 0, 0);
      acc01 = __builtin_amdgcn_mfma_f32_16x16x32_bf16(ah0, bl1, acc01, 0, 0, 0);
      acc01 = __builtin_amdgcn_mfma_f32_16x16x32_bf16(al0, bh1, acc01, 0, 0, 0);
      acc10 = __builtin_amdgcn_mfma_f32_16x16x32_bf16(ah1, bh0, acc10, 0, 0, 0);
      acc10 = __builtin_amdgcn_mfma_f32_16x16x32_bf16(ah1, bl0, acc10, 0, 0, 0);
      acc10 = __builtin_amdgcn_mfma_f32_16x16x32_bf16(al1, bh0, acc10, 0, 0, 0);
      acc11 = __builtin_amdgcn_mfma_f32_16x16x32_bf16(ah1, bh1, acc11, 0, 0, 0);
      acc11 = __builtin_amdgcn_mfma_f32_16x16x32_bf16(ah1, bl1, acc11, 0, 0, 0);
      acc11 = __builtin_amdgcn_mfma_f32_16x16x32_bf16(al1, bh1, acc11, 0, 0, 0);
    }
    __syncthreads();
  }
#pragma unroll
  for (int mi = 0; mi < 2; ++mi)
#pragma unroll
  for (int ni = 0; ni < 2; ++ni){
    f32x4 a = (mi == 0) ? ((ni == 0) ? acc00 : acc01) : ((ni == 0) ? acc10 : acc11);
#pragma unroll
    for (int r = 0; r < 4; ++r){
      int i = m0 + wm + mi*16 + q*4 + r;
      int n = n0 + wn + ni*16 + l16;
      float v = a[r];
      if constexpr (MODE == 0) v += bias[n];
      else                     v *= 1.0f / sqrtf((float)(deg[i] + 1));
      outF[(size_t)i*N + n] = v;
    }
  }
}

// --------------- fused dual GEMM for N=64 stages (verified R15) -------------
__global__ __launch_bounds__(256) void mgemm2_kernel(const float* __restrict__ A, const float* __restrict__ Bt1,
                                                     int K1, const float* __restrict__ bias1,
                                                     const float* __restrict__ Bt2, const int* __restrict__ deg,
                                                     float* __restrict__ hOut, float* __restrict__ zsOut){
  constexpr int LDT = 72;
  __shared__ u16 Ah[64*LDT], Al[64*LDT], Bh[64*LDT], Bl[64*LDT];
  const int m0 = blockIdx.x*64;
  const int tid = threadIdx.x;
  const int wave = tid >> 6, lane = tid & 63;
  const int wm = (wave>>1)*32, wn = (wave&1)*32;
  const int q = lane >> 4, l16 = lane & 15;
  const int sr = tid >> 2, sc = (tid & 3)*16;
  f32x4 acc00 = {}, acc01 = {}, acc10 = {}, acc11 = {};
  for (int k0 = 0; k0 < K1; k0 += 64){
    const float* Ag = A   + (size_t)(m0+sr)*K1 + k0 + sc;
    const float* Bg = Bt1 + (size_t)sr*K1 + k0 + sc;
#pragma unroll
    for (int v4 = 0; v4 < 4; ++v4){
      float4 av = ((const float4*)Ag)[v4];
      float4 bv = ((const float4*)Bg)[v4];
      int o = sr*LDT + sc + v4*4;
      splitbf(av.x, Ah[o+0], Al[o+0]); splitbf(av.y, Ah[o+1], Al[o+1]);
      splitbf(av.z, Ah[o+2], Al[o+2]); splitbf(av.w, Ah[o+3], Al[o+3]);
      splitbf(bv.x, Bh[o+0], Bl[o+0]); splitbf(bv.y, Bh[o+1], Bl[o+1]);
      splitbf(bv.z, Bh[o+2], Bl[o+2]); splitbf(bv.w, Bh[o+3], Bl[o+3]);
    }
    __syncthreads();
#pragma unroll
    for (int ks = 0; ks < 2; ++ks){
      const int kb = ks*32 + q*8;
      short8 ah0 = *(const short8*)&Ah[(wm      + l16)*LDT + kb];
      short8 al0 = *(const short8*)&Al[(wm      + l16)*LDT + kb];
      short8 ah1 = *(const short8*)&Ah[(wm + 16 + l16)*LDT + kb];
      short8 al1 = *(const short8*)&Al[(wm + 16 + l16)*LDT + kb];
      short8 bh0 = *(const short8*)&Bh[(wn      + l16)*LDT + kb];
      short8 bl0 = *(const short8*)&Bl[(wn      + l16)*LDT + kb];
      short8 bh1 = *(const short8*)&Bh[(wn + 16 + l16)*LDT + kb];
      short8 bl1 = *(const short8*)&Bl[(wn + 16 + l16)*LDT + kb];
      acc00 = __builtin_amdgcn_mfma_f32_16x16x32_bf16(ah0, bh0, acc00, 0, 0, 0);
      acc00 = __builtin_amdgcn_mfma_f32_16x16x32_bf16(ah0, bl0, acc00, 0, 0, 0);
      acc00 = __builtin_amdgcn_mfma_f32_16x16x32_bf16(al0, bh0, acc00, 0, 0, 0);
      acc01 = __builtin_amdgcn_mfma_f32_16x16x32_bf16(ah0, bh1, acc01, 0, 0, 0);
      acc01 = __builtin_amdgcn_mfma_f32_16x16x32_bf16(ah0, bl1, acc01, 0, 0, 0);
      acc01 = __builtin_amdgcn_mfma_f32_16x16x32_bf16(al0, bh1, acc01, 0, 0, 0);
      acc10 = __builtin_amdgcn_mfma_f32_16x16x32_bf16(ah1, bh0, acc10, 0, 0, 0);
      acc10 = __builtin_amdgcn_mfma_f32_16x16x32_bf16(ah1, bl0, acc10, 0, 0, 0);
      acc10 = __builtin_amdgcn_mfma_f32_16x16x32_bf16(al1, bh0, acc10, 0, 0, 0);
      acc11 = __builtin_amdgcn_mfma_f32_16x16x32_bf16(ah1, bh1, acc11, 0, 0, 0);
      acc11 = __builtin_amdgcn_mfma_f32_16x16x32_bf16(ah1, bl1, acc11, 0, 0, 0);
      acc11 = __builtin_amdgcn_mfma_f32_16x16x32_bf16(al1, bh1, acc11, 0, 0, 0);
    }
    __syncthreads();
  }
#pragma unroll
  for (int mi = 0; mi < 2; ++mi)
#pragma unroll
  for (int ni = 0; ni < 2; ++ni){
    f32x4 a = (mi == 0) ? ((ni == 0) ? acc00 : acc01) : ((ni == 0) ? acc10 : acc11);
#pragma unroll
    for (int r = 0; r < 4; ++r){
      int il = wm + mi*16 + q*4 + r;
      int n  = wn + ni*16 + l16;
      float v = a[r] + bias1[n];
      hOut[(size_t)(m0 + il)*64 + n] = v;
      u16 hh, ll;
      splitbf(v, hh, ll);
      Ah[il*LDT + n] = hh;
      Al[il*LDT + n] = ll;
    }
  }
  __syncthreads();
  {
    const float* Bg = Bt2 + (size_t)sr*64 + sc;
#pragma unroll
    for (int v4 = 0; v4 < 4; ++v4){
      float4 bv = ((const float4*)Bg)[v4];
      int o = sr*LDT + sc + v4*4;
      splitbf(bv.x, Bh[o+0], Bl[o+0]); splitbf(bv.y, Bh[o+1], Bl[o+1]);
      splitbf(bv.z, Bh[o+2], Bl[o+2]); splitbf(bv.w, Bh[o+3], Bl[o+3]);
    }
  }
  __syncthreads();
  f32x4 z00 = {}, z01 = {}, z10 = {}, z11 = {};
#pragma unroll
  for (int ks = 0; ks < 2; ++ks){
    const int kb = ks*32 + q*8;
    short8 ah0 = *(const short8*)&Ah[(wm      + l16)*LDT + kb];
    short8 al0 = *(const short8*)&Al[(wm      + l16)*LDT + kb];
    short8 ah1 = *(const short8*)&Ah[(wm + 16 + l16)*LDT + kb];
    short8 al1 = *(const short8*)&Al[(wm + 16 + l16)*LDT + kb];
    short8 bh0 = *(const short8*)&Bh[(wn      + l16)*LDT + kb];
    short8 bl0 = *(const short8*)&Bl[(wn      + l16)*LDT + kb];
    short8 bh1 = *(const short8*)&Bh[(wn + 16 + l16)*LDT + kb];
    short8 bl1 = *(const short8*)&Bl[(wn + 16 + l16)*LDT + kb];
    z00 = __builtin_amdgcn_mfma_f32_16x16x32_bf16(ah0, bh0, z00, 0, 0, 0);
    z00 = __builtin_amdgcn_mfma_f32_16x16x32_bf16(ah0, bl0, z00, 0, 0, 0);
    z00 = __builtin_amdgcn_mfma_f32_16x16x32_bf16(al0, bh0, z00, 0, 0, 0);
    z01 = __builtin_amdgcn_mfma_f32_16x16x32_bf16(ah0, bh1, z01, 0, 0, 0);
    z01 = __builtin_amdgcn_mfma_f32_16x16x32_bf16(ah0, bl1, z01, 0, 0, 0);
    z01 = __builtin_amdgcn_mfma_f32_16x16x32_bf16(al0, bh1, z01, 0, 0, 0);
    z10 = __builtin_amdgcn_mfma_f32_16x16x32_bf16(ah1, bh0, z10, 0, 0, 0);
    z10 = __builtin_amdgcn_mfma_f32_16x16x32_bf16(ah1, bl0, z10, 0, 0, 0);
    z10 = __builtin_amdgcn_mfma_f32_16x16x32_bf16(al1, bh0, z10, 0, 0, 0);
    z11 = __builtin_amdgcn_mfma_f32_16x16x32_bf16(ah1, bh1, z11, 0, 0, 0);
    z11 = __builtin_amdgcn_mfma_f32_16x16x32_bf16(ah1, bl1, z11, 0, 0, 0);
    z11 = __builtin_amdgcn_mfma_f32_16x16x32_bf16(al1, bh1, z11, 0, 0, 0);
  }
#pragma unroll
  for (int mi = 0; mi < 2; ++mi)
#pragma unroll
  for (int ni = 0; ni < 2; ++ni){
    f32x4 a = (mi == 0) ? ((ni == 0) ? z00 : z01) : ((ni == 0) ? z10 : z11);
#pragma unroll
    for (int r = 0; r < 4; ++r){
      int i = m0 + wm + mi*16 + q*4 + r;
      int n = wn + ni*16 + l16;
      zsOut[(size_t)i*64 + n] = a[r] * (1.0f / sqrtf((float)(deg[i] + 1)));
    }
  }
}

// --------------- split-K bitmask-MFMA aggregation (partials) ----------------
template<int F>
__global__ __launch_bounds__(256) void maggp_kernel(const float* __restrict__ zs,
                                                    const u64* __restrict__ rowb,
                                                    float* __restrict__ part, int KCH){
  const int m0 = blockIdx.x*64, n0 = blockIdx.y*64, kc0 = blockIdx.z*KCH;
  const int tid = threadIdx.x;
  const int wave = tid >> 6, lane = tid & 63;
  const int wm = (wave>>1)*32, wn = (wave&1)*32;
  const int q = lane >> 4, l16 = lane & 15;
  f32x4 acc00 = {}, acc01 = {}, acc10 = {}, acc11 = {};
  for (int k0 = kc0; k0 < kc0 + KCH; k0 += 64){
    const int wd = k0 >> 6;
    u64 w0 = rowb[(size_t)(m0 + wm      + l16)*32 + wd];
    u64 w1 = rowb[(size_t)(m0 + wm + 16 + l16)*32 + wd];
#pragma unroll
    for (int ks = 0; ks < 2; ++ks){
      const int kk = ks*32 + q*8;
      u32 by0 = (u32)(w0 >> kk) & 0xFFu;
      u32 by1 = (u32)(w1 >> kk) & 0xFFu;
      short8 a0, a1;
#pragma unroll
      for (int j = 0; j < 8; ++j){
        a0[j] = (short)(((by0 >> j) & 1u) ? 0x3F80 : 0);
        a1[j] = (short)(((by1 >> j) & 1u) ? 0x3F80 : 0);
      }
      const float* B0 = zs + (size_t)(k0 + kk)*F + n0;
      short8 bh0, bl0, bh1, bl1;
#pragma unroll
      for (int j = 0; j < 8; ++j){
        u16 hh, ll;
        splitbf(B0[(size_t)j*F + wn      + l16], hh, ll); bh0[j] = (short)hh; bl0[j] = (short)ll;
        splitbf(B0[(size_t)j*F + wn + 16 + l16], hh, ll); bh1[j] = (short)hh; bl1[j] = (short)ll;
      }
      acc00 = __builtin_amdgcn_mfma_f32_16x16x32_bf16(a0, bh0, acc00, 0, 0, 0);
      acc00 = __builtin_amdgcn_mfma_f32_16x16x32_bf16(a0, bl0, acc00, 0, 0, 0);
      acc01 = __builtin_amdgcn_mfma_f32_16x16x32_bf16(a0, bh1, acc01, 0, 0, 0);
      acc01 = __builtin_amdgcn_mfma_f32_16x16x32_bf16(a0, bl1, acc01, 0, 0, 0);
      acc10 = __builtin_amdgcn_mfma_f32_16x16x32_bf16(a1, bh0, acc10, 0, 0, 0);
      acc10 = __builtin_amdgcn_mfma_f32_16x16x32_bf16(a1, bl0, acc10, 0, 0, 0);
      acc11 = __builtin_amdgcn_mfma_f32_16x16x32_bf16(a1, bh1, acc11, 0, 0, 0);
      acc11 = __builtin_amdgcn_mfma_f32_16x16x32_bf16(a1, bl1, acc11, 0, 0, 0);
    }
  }
  float* p = part + (size_t)blockIdx.z*NN*F;
#pragma unroll
  for (int mi = 0; mi < 2; ++mi)
#pragma unroll
  for (int ni = 0; ni < 2; ++ni){
    f32x4 a = (mi == 0) ? ((ni == 0) ? acc00 : acc01) : ((ni == 0) ? acc10 : acc11);
#pragma unroll
    for (int r = 0; r < 4; ++r){
      int i = m0 + wm + mi*16 + q*4 + r;
      int n = n0 + wn + ni*16 + l16;
      p[(size_t)i*F + n] = a[r];
    }
  }
}

// --------------- split-K reduce + GCN epilogue ------------------------------
template<int F>
__global__ __launch_bounds__(256) void magge_kernel(const float* __restrict__ part,
                                                    const float* __restrict__ zs, const float* __restrict__ h,
                                                    const float* __restrict__ bias, const int* __restrict__ deg,
                                                    int KS, float wgt, int doRelu,
                                                    float* __restrict__ outF, float* __restrict__ outD){
  int g = blockIdx.x*256 + threadIdx.x;   // 2048*F
  int n = g & (F - 1);
  int i = g / F;
  float y = 0.f;
  for (int s = 0; s < KS; ++s) y += part[(size_t)s*NN*F + g];
  float di = 1.0f / sqrtf((float)(deg[i] + 1));
  float o = di*(y + zs[g]) + bias[n];
  if (doRelu) o = fmaxf(o, 0.f);
  float xn = h[g] + wgt*o;
  outF[g] = xn;
  if (outD) outD[g] = xn;
}

static inline char* wso(void* ws, size_t& off, size_t bytes){
  char* p = (char*)ws + off;
  off += (bytes + 255) & ~(size_t)255;
  return p;
}

extern "C" void kernel_launch(void* const* d_in, const int* in_sizes, int n_in,
                              void* d_out, int out_size, void* d_ws, size_t ws_size,
                              hipStream_t stream){
  // ---- regression guards ----
  static const int EXP_SIZES[21] = {
    2048*512, 2048*2048, 2048*2048,
    512*256, 256, 256*62, 62, 62*64, 64,
    256*256, 256, 62*62, 62, 64*64, 64,
    64*64, 64, 64*64, 64, 64*64, 64
  };
  float sentinel = 0.f;
  if (n_in != 21) sentinel = 8800000.f;
  if (sentinel == 0.f){
    for (int i = 0; i < 21; ++i)
      if (in_sizes[i] != EXP_SIZES[i]){ sentinel = 100000.f*(float)(i+1); break; }
  }
  if (sentinel == 0.f && out_size != 2048*64) sentinel = 6600000.f;

  // ---- workspace layout (zeroed prefix: dflag|ap_cnt|deg6) ----
  size_t off = 0;
  int*   dflag  = (int*)  wso(d_ws, off, 256);
  int*   ap_cnt = (int*)  wso(d_ws, off, NN*4);
  int*   deg6   = (int*)  wso(d_ws, off, (size_t)6*NN*4);
  size_t zero_bytes = off;
  int*   ap_idx = (int*)  wso(d_ws, off, NN*64*4);
  u64*   colA   = (u64*)  wso(d_ws, off, (size_t)NN*32*8);
  u64*   colB   = (u64*)  wso(d_ws, off, (size_t)NN*32*8);
  u64*   colU   = (u64*)  wso(d_ws, off, (size_t)NN*32*8);
  u64*   rowb6  = (u64*)  wso(d_ws, off, (size_t)6*NN*32*8);
  float* xf     = (float*)wso(d_ws, off, (size_t)NN*512*4);
  float* part   = (float*)wso(d_ws, off, (size_t)16*NN*64*4);   // 8 MB split-K partials
  float *tl1 = (float*)wso(d_ws, off, 256*512*4), *tg1 = (float*)wso(d_ws, off, 256*256*4);
  float *tl2 = (float*)wso(d_ws, off,  64*256*4), *tg2 = (float*)wso(d_ws, off,  64*64*4);
  float *tl3 = (float*)wso(d_ws, off,   64*64*4), *tg3 = (float*)wso(d_ws, off,  64*64*4);
  float *tg4 = (float*)wso(d_ws, off,   64*64*4), *tg5 = (float*)wso(d_ws, off,  64*64*4);
  float *tg6 = (float*)wso(d_ws, off,   64*64*4);
  float *obl1 = (float*)wso(d_ws, off, 256*4), *obg1 = (float*)wso(d_ws, off, 256*4);
  float *obl2 = (float*)wso(d_ws, off, 64*4),  *obg2 = (float*)wso(d_ws, off, 64*4);
  float *obl3 = (float*)wso(d_ws, off, 64*4),  *obg3 = (float*)wso(d_ws, off, 64*4);
  float *obg4 = (float*)wso(d_ws, off, 64*4),  *obg5 = (float*)wso(d_ws, off, 64*4);
  float *obg6 = (float*)wso(d_ws, off, 64*4);
  float* hF   = (float*)wso(d_ws, off, (size_t)NN*256*4);
  float* zs   = (float*)wso(d_ws, off, (size_t)NN*256*4);
  float* xF   = (float*)wso(d_ws, off, (size_t)NN*256*4);

  if (sentinel == 0.f && off > ws_size) sentinel = 7700000.f;

  if (sentinel != 0.f){
    sentinel_kernel<<<(NN*64 + 255)/256, 256, 0, stream>>>((float*)d_out, sentinel);
    return;
  }

  const void* x_in = d_in[0];
  const void* An   = d_in[1];
  const void* Ap   = d_in[2];

  hipMemsetAsync(d_ws, 0, zero_bytes, stream);   // dflag + ap_cnt + deg6
  probe_kernel<<<256, 256, 0, stream>>>((const u32*)Ap, dflag);

  InputArgs ia;
  ia.Ap = Ap; ia.An = An; ia.x = x_in;
  ia.ap_cnt = ap_cnt; ia.ap_idx = ap_idx;
  ia.last = colA; ia.uni = colU; ia.xf = xf;
  ia.wl1=d_in[3];  ia.bl1=d_in[4];
  ia.wl2=d_in[5];  ia.bl2=d_in[6];
  ia.wl3=d_in[7];  ia.bl3=d_in[8];
  ia.wg1=d_in[9];  ia.bg1=d_in[10];
  ia.wg2=d_in[11]; ia.bg2=d_in[12];
  ia.wg3=d_in[13]; ia.bg3=d_in[14];
  ia.wg4=d_in[15]; ia.bg4=d_in[16];
  ia.wg5=d_in[17]; ia.bg5=d_in[18];
  ia.wg6=d_in[19]; ia.bg6=d_in[20];
  ia.tl1=tl1; ia.tg1=tg1; ia.tl2=tl2; ia.tg2=tg2; ia.tl3=tl3;
  ia.tg3=tg3; ia.tg4=tg4; ia.tg5=tg5; ia.tg6=tg6;
  ia.obl1=obl1; ia.obg1=obg1; ia.obl2=obl2; ia.obg2=obg2; ia.obl3=obl3;
  ia.obg3=obg3; ia.obg4=obg4; ia.obg5=obg5; ia.obg6=obg6;
  ia.flag = dflag;
  input_kernel<<<17152, 256, 0, stream>>>(ia);

  // ---- bit pipeline: 6 fused expand+transpose+deg steps ----
  {
    u64 *src = colA, *dst = colB;
    for (int s = 0; s < 6; ++s){
      bitstep_kernel<<<dim3(32,32), 64, 0, stream>>>(src, dst, colU, ap_cnt, ap_idx,
                                                     rowb6 + (size_t)s*NN*32, deg6 + s*NN,
                                                     s > 0 ? 1 : 0);
      if (s > 0){ u64* t = src; src = dst; dst = t; }
    }
  }

  const u64* rb[6]; const int* dg[6];
  for (int s = 0; s < 6; ++s){ rb[s] = rowb6 + (size_t)s*NN*32; dg[s] = deg6 + s*NN; }

  // ---- stage 0 (F=256) ----
  mgemm_kernel<0><<<dim3(32,4), 256, 0, stream>>>(xf, tl1, 256, 512, obl1, nullptr, hF);
  mgemm_kernel<1><<<dim3(32,4), 256, 0, stream>>>(hF, tg1, 256, 256, nullptr, dg[0], zs);
  maggp_kernel<256><<<dim3(32,4,4), 256, 0, stream>>>(zs, rb[0], part, 512);
  magge_kernel<256><<<(NN*256)/256, 256, 0, stream>>>(part, zs, hF, obg1, dg[0], 4,
                                                      1.0f, 1, xF, nullptr);
  // ---- stage 1 (dual GEMM) ----
  mgemm2_kernel<<<dim3(32,1), 256, 0, stream>>>(xF, tl2, 256, obl2, tg2, dg[1], hF, zs);
  maggp_kernel<64><<<dim3(32,1,8), 256, 0, stream>>>(zs, rb[1], part, 256);
  magge_kernel<64><<<(NN*64)/256, 256, 0, stream>>>(part, zs, hF, obg2, dg[1], 8,
                                                    1.0f, 1, xF, nullptr);
  // ---- stage 2 (dual GEMM) ----
  mgemm2_kernel<<<dim3(32,1), 256, 0, stream>>>(xF, tl3, 64, obl3, tg3, dg[2], hF, zs);
  maggp_kernel<64><<<dim3(32,1,8), 256, 0, stream>>>(zs, rb[2], part, 256);
  magge_kernel<64><<<(NN*64)/256, 256, 0, stream>>>(part, zs, hF, obg3, dg[2], 8,
                                                    0.5f, 1, xF, nullptr);
  // ---- stages 3-5 ----
  const float* tgs[3]  = {tg4, tg5, tg6};
  const float* obs[3]  = {obg4, obg5, obg6};
  const float  wg3_[3] = {0.5f, 0.25f, 0.25f};
  const int    rl3_[3] = {1, 1, 0};
  for (int s = 3; s < 6; ++s){
    mgemm_kernel<1><<<dim3(32,1), 256, 0, stream>>>(xF, tgs[s-3], 64, 64, nullptr, dg[s], zs);
    maggp_kernel<64><<<dim3(32,1,8), 256, 0, stream>>>(zs, rb[s], part, 256);
    float* outD = (s == 5) ? (float*)d_out : nullptr;
    magge_kernel<64><<<(NN*64)/256, 256, 0, stream>>>(part, zs, xF, obs[s-3], dg[s], 8,
                                                      wg3_[s-3], rl3_[s-3], xF, outD);
  }
}